// Round 14
// baseline (376.901 us; speedup 1.0000x reference)
//
#include <hip/hip_runtime.h>
#include <math.h>

#define VOL   128
#define V2    (VOL*VOL)
#define V3    (VOL*VOL*VOL)
#define NPTS  262144
#define LATD  16
#define BATCH 8
#define FACTORF 64.0f
#define NBINS2 (VOL*VOL*BATCH)        // 131072 target bins, batch-major
#define RZ 8
#define RY 4
#define REG_PER_B ((VOL/RZ)*(VOL/RY)) // 512
#define SCAN_WGS 512

// ws layout (bytes)
#define WS_HBUF   0u
#define WS_HIST   256u
#define WS_START  (WS_HIST + NBINS2*4u)          // 524544
#define WS_CURSOR (WS_START + (NBINS2+4u)*4u)    // 1048848 (sentinel + pad)
#define WS_WGSUM  (WS_CURSOR + NBINS2*4u)        // 1573136
#define WS_COORDS (WS_WGSUM + 2048u)             // 1575184 (16-aligned)
#define WS_FULL   (WS_COORDS + (size_t)NPTS*BATCH*16u)  // 35129616

// Round-to-nearest-even float -> bf16 -> float (ml_dtypes / XLA bf16 RNE)
__device__ __forceinline__ float bf16r(float x) {
    unsigned u = __float_as_uint(x);
    u = (u + 0x7fffu + ((u >> 16) & 1u)) & 0xffff0000u;
    return __uint_as_float(u);
}

// SIREN MLP, per-op bf16 (verified round 11).
__global__ void mlp_kernel(const float* __restrict__ x,
                           const float* __restrict__ W0,
                           const float* __restrict__ b0,
                           const float* __restrict__ Wh,
                           const float* __restrict__ bh,
                           float* __restrict__ hout) {
    int b = threadIdx.x;
    if (b >= BATCH) return;
    float xb[LATD];
    #pragma unroll
    for (int i = 0; i < LATD; ++i) xb[i] = bf16r(x[b*LATD + i]);
    float h[8];
    #pragma unroll
    for (int j = 0; j < 8; ++j) {
        float acc = 0.f;
        #pragma unroll
        for (int i = 0; i < LATD; ++i) acc += xb[i] * bf16r(W0[i*8 + j]);
        float t = bf16r(acc);
        t = bf16r(t + bf16r(b0[j]));
        t = bf16r(30.0f * t);
        h[j] = bf16r(sinf(t));
    }
    for (int l = 0; l < 4; ++l) {
        float nh[8];
        #pragma unroll
        for (int j = 0; j < 8; ++j) {
            float acc = 0.f;
            #pragma unroll
            for (int r = 0; r < 8; ++r) acc += h[r] * bf16r(Wh[(l*8 + r)*8 + j]);
            float t = bf16r(acc);
            t = bf16r(t + bf16r(bh[l*8 + j]));
            float s = bf16r(sinf(t));
            nh[j] = bf16r(h[j] + s);
        }
        #pragma unroll
        for (int j = 0; j < 8; ++j) h[j] = nh[j];
    }
    #pragma unroll
    for (int j = 0; j < 8; ++j) hout[b*8 + j] = h[j];
}

// PASS 0: histogram target bins. PASS 1: write coords sorted by target bin.
// Both passes compute IDENTICAL IEEE sequences -> identical bins.
template<int PASS>
__global__ __launch_bounds__(256) void binpass_kernel(
    const float* __restrict__ Wf, const float* __restrict__ bfv_g,
    const float* __restrict__ rv, const int* __restrict__ inds,
    const float* __restrict__ hbuf, unsigned* __restrict__ hc,
    float4* __restrict__ coords_s)
{
    __shared__ float hs[64];
    if (threadIdx.x < 64) hs[threadIdx.x] = hbuf[threadIdx.x];
    __syncthreads();
    int n = blockIdx.x * 256 + threadIdx.x;
    if (n >= NPTS) return;
    int iz = inds[n*3], iy = inds[n*3+1], ix = inds[n*3+2];
    float cnx = ((float)ix - FACTORF) / FACTORF;
    float cny = ((float)iy - FACTORF) / FACTORF;
    float cnz = ((float)iz - FACTORF) / FACTORF;
    float val0 = rv[n];
    float4 bfv = ((const float4*)bfv_g)[n];
    float4 wf[8];
    #pragma unroll
    for (int r = 0; r < 8; ++r)
        wf[r] = ((const float4*)(Wf + (size_t)r * 4 * NPTS))[n];
    #pragma unroll
    for (int b = 0; b < BATCH; ++b) {
        float o0 = bfv.x, o1 = bfv.y, o2 = bfv.z, o3 = bfv.w;
        #pragma unroll
        for (int r = 0; r < 8; ++r) {
            float hv = hs[b*8 + r];
            o0 = fmaf(hv, wf[r].x, o0);
            o1 = fmaf(hv, wf[r].y, o1);
            o2 = fmaf(hv, wf[r].z, o2);
            o3 = fmaf(hv, wf[r].w, o3);
        }
        float4 c;
        c.x = FACTORF * (cnx + o0) + FACTORF;
        c.y = FACTORF * (cny + o1) + FACTORF;
        c.z = FACTORF * (cnz + o2) + FACTORF;
        c.w = val0 + o3;
        int bz = (int)floorf(c.z), by = (int)floorf(c.y);
        unsigned bin = ((unsigned)b << 14) |
                       ((unsigned)(bz & 127) << 7) | (unsigned)(by & 127);
        if (PASS == 0) {
            atomicAdd(&hc[bin], 1u);
        } else {
            unsigned pos = atomicAdd(&hc[bin], 1u);
            coords_s[pos] = c;
        }
    }
}

__global__ __launch_bounds__(256) void scanA_kernel(const unsigned* __restrict__ hist,
                                                    unsigned* __restrict__ wgsum) {
    __shared__ unsigned s[256];
    int t = threadIdx.x;
    s[t] = hist[blockIdx.x * 256 + t];
    __syncthreads();
    for (int off = 128; off > 0; off >>= 1) {
        if (t < off) s[t] += s[t + off];
        __syncthreads();
    }
    if (t == 0) wgsum[blockIdx.x] = s[0];
}

__global__ __launch_bounds__(256) void scanB_kernel(unsigned* __restrict__ wgsum,
                                                    unsigned* __restrict__ binstart) {
    __shared__ unsigned s[SCAN_WGS];
    int t = threadIdx.x;
    s[t] = wgsum[t]; s[t + 256] = wgsum[t + 256];
    __syncthreads();
    if (t == 0) {
        unsigned run = 0;
        for (int i = 0; i < SCAN_WGS; ++i) { unsigned v = s[i]; s[i] = run; run += v; }
        binstart[NBINS2] = run;   // sentinel = total entries (2M)
    }
    __syncthreads();
    wgsum[t] = s[t]; wgsum[t + 256] = s[t + 256];
}

__global__ __launch_bounds__(256) void scanC_kernel(const unsigned* __restrict__ hist,
                                                    const unsigned* __restrict__ wgsum,
                                                    unsigned* __restrict__ binstart,
                                                    unsigned* __restrict__ cursor) {
    __shared__ unsigned s[256];
    int t = threadIdx.x;
    int idx = blockIdx.x * 256 + t;
    unsigned h = hist[idx];
    s[t] = h; __syncthreads();
    for (int off = 1; off < 256; off <<= 1) {
        unsigned v = (t >= off) ? s[t - off] : 0u;
        __syncthreads();
        s[t] += v;
        __syncthreads();
    }
    unsigned excl = s[t] - h + wgsum[blockIdx.x];
    binstart[idx] = excl;
    cursor[idx]   = excl;
}

// One wg = (batch, RZ x RY x 128 region). Targets always in {bin, bin+1} per
// axis (mod 128), so a 1-bin low-side halo suffices for ANY displacement.
__global__ __launch_bounds__(256) void region_kernel(
    const float4* __restrict__ coords_s, const unsigned* __restrict__ binstart,
    float* __restrict__ out)
{
    __shared__ float tile[RZ*RY*VOL];   // 16 KB
    int tid = threadIdx.x;
    int b   = blockIdx.x >> 9;
    int rid = blockIdx.x & (REG_PER_B - 1);
    int z0 = (rid >> 5) * RZ, y0 = (rid & 31) * RY;
    for (int i = tid; i < RZ*RY*VOL; i += 256) tile[i] = 0.f;
    __syncthreads();

    const int ox[8] = {0,1,0,0,0,1,1,1};
    const int oy[8] = {0,0,1,0,1,0,1,1};
    const int oz[8] = {0,0,0,1,1,1,0,1};

    int ya0, ya1, yb0, yb1;
    if (y0 == 0) { ya0 = VOL-1; ya1 = VOL; yb0 = 0; yb1 = RY; }
    else         { ya0 = y0-1;  ya1 = y0+RY; yb0 = 0; yb1 = 0; }

    for (int zr = z0 - 1; zr < z0 + RZ; ++zr) {
        int zz = (zr + VOL) & (VOL-1);
        unsigned base = ((unsigned)b << 14) | ((unsigned)zz << 7);
        for (int sg = 0; sg < 2; ++sg) {
            int a  = sg ? yb0 : ya0;
            int e2 = sg ? yb1 : ya1;
            if (a >= e2) continue;
            unsigned s = binstart[base + a];
            unsigned e = binstart[base + e2];
            for (unsigned i = s + tid; i < e; i += 256) {
                float4 c = coords_s[i];
                float fxf = floorf(c.x), fyf = floorf(c.y), fzf = floorf(c.z);
                int bx = (int)fxf, by = (int)fyf, bz = (int)fzf;
                float fx = c.x - fxf, fy = c.y - fyf, fz = c.z - fzf;
                float gx = 1.f - fx, gy = 1.f - fy, gz = 1.f - fz;
                float val = c.w;
                float w[8] = {gx*gy*gz, fx*gy*gz, gx*fy*gz, gx*gy*fz,
                              gx*fy*fz, fx*gy*fz, fx*fy*gz, fx*fy*fz};
                #pragma unroll
                for (int o = 0; o < 8; ++o) {
                    int Z = (bz + oz[o]) & 127, dz = Z - z0;
                    if ((unsigned)dz >= RZ) continue;
                    int Y = (by + oy[o]) & 127, dy = Y - y0;
                    if ((unsigned)dy >= RY) continue;
                    int X = (bx + ox[o]) & 127;
                    atomicAdd(&tile[(dz << 9) + (dy << 7) + X], val * w[o]);
                }
            }
        }
    }
    __syncthreads();
    size_t ob = (size_t)b * V3;
    for (int i = tid; i < RZ*RY*VOL; i += 256) {
        int lz = i >> 9, ly = (i >> 7) & (RY-1), lx = i & 127;
        out[ob + (size_t)(z0+lz)*V2 + (y0+ly)*VOL + lx] = tile[i];
    }
}

// Fallback (round-11 verified path) if workspace too small.
__global__ __launch_bounds__(256) void scatter_fallback(
    const float* __restrict__ Wf, const float* __restrict__ bfv_g,
    const float* __restrict__ rv, const int* __restrict__ inds,
    const float* __restrict__ hbuf, float* __restrict__ out)
{
    __shared__ float hs[BATCH*8];
    if (threadIdx.x < BATCH*8) hs[threadIdx.x] = hbuf[threadIdx.x];
    __syncthreads();
    int n = blockIdx.x * blockDim.x + threadIdx.x;
    if (n >= NPTS) return;
    int iz = inds[n*3 + 0], iy = inds[n*3 + 1], ix = inds[n*3 + 2];
    float cnx = ((float)ix - FACTORF) / FACTORF;
    float cny = ((float)iy - FACTORF) / FACTORF;
    float cnz = ((float)iz - FACTORF) / FACTORF;
    float val0 = rv[n];
    float4 bfv = ((const float4*)bfv_g)[n];
    float4 wf[8];
    #pragma unroll
    for (int r = 0; r < 8; ++r)
        wf[r] = ((const float4*)(Wf + (size_t)r * 4 * NPTS))[n];
    static const int offs[8][3] = {{0,0,0},{1,0,0},{0,1,0},{0,0,1},
                                   {0,1,1},{1,0,1},{1,1,0},{1,1,1}};
    #pragma unroll
    for (int b = 0; b < BATCH; ++b) {
        float o0 = bfv.x, o1 = bfv.y, o2 = bfv.z, o3 = bfv.w;
        #pragma unroll
        for (int r = 0; r < 8; ++r) {
            float hv = hs[b*8 + r];
            o0 = fmaf(hv, wf[r].x, o0);
            o1 = fmaf(hv, wf[r].y, o1);
            o2 = fmaf(hv, wf[r].z, o2);
            o3 = fmaf(hv, wf[r].w, o3);
        }
        float cx = FACTORF * (cnx + o0) + FACTORF;
        float cy = FACTORF * (cny + o1) + FACTORF;
        float cz = FACTORF * (cnz + o2) + FACTORF;
        float val = val0 + o3;
        float fxf = floorf(cx), fyf = floorf(cy), fzf = floorf(cz);
        int bx = (int)fxf, by = (int)fyf, bz = (int)fzf;
        float fx = cx - fxf, fy = cy - fyf, fz = cz - fzf;
        float gx = 1.f - fx, gy = 1.f - fy, gz = 1.f - fz;
        float w[8] = {gx*gy*gz, fx*gy*gz, gx*fy*gz, gx*gy*fz,
                      gx*fy*fz, fx*gy*fz, fx*fy*gz, fx*fy*fz};
        float* ob = out + (size_t)b * V3;
        #pragma unroll
        for (int o = 0; o < 8; ++o) {
            int X = (bx + offs[o][0]) & (VOL-1);
            int Y = (by + offs[o][1]) & (VOL-1);
            int Z = (bz + offs[o][2]) & (VOL-1);
            atomicAdd(ob + (size_t)Z*V2 + Y*VOL + X, val * w[o]);
        }
    }
}

extern "C" void kernel_launch(void* const* d_in, const int* in_sizes, int n_in,
                              void* d_out, int out_size, void* d_ws, size_t ws_size,
                              hipStream_t stream) {
    const float* x    = (const float*)d_in[0];
    const float* W0   = (const float*)d_in[1];
    const float* b0   = (const float*)d_in[2];
    const float* Wh   = (const float*)d_in[3];
    const float* bh   = (const float*)d_in[4];
    const float* Wf   = (const float*)d_in[5];
    const float* bf   = (const float*)d_in[6];
    const float* rv   = (const float*)d_in[7];
    const int*   inds = (const int*)d_in[8];
    float* out = (float*)d_out;
    char*  ws  = (char*)d_ws;

    float*    hbuf     = (float*)(ws + WS_HBUF);
    unsigned* hist     = (unsigned*)(ws + WS_HIST);
    unsigned* binstart = (unsigned*)(ws + WS_START);
    unsigned* cursor   = (unsigned*)(ws + WS_CURSOR);
    unsigned* wgsum    = (unsigned*)(ws + WS_WGSUM);
    float4*   coords_s = (float4*)(ws + WS_COORDS);

    mlp_kernel<<<1, 64, 0, stream>>>(x, W0, b0, Wh, bh, hbuf);

    if (ws_size >= (size_t)WS_FULL) {
        hipMemsetAsync(hist, 0, NBINS2*4, stream);
        binpass_kernel<0><<<NPTS/256, 256, 0, stream>>>(Wf, bf, rv, inds, hbuf,
                                                        hist, coords_s);
        scanA_kernel<<<SCAN_WGS, 256, 0, stream>>>(hist, wgsum);
        scanB_kernel<<<1, 256, 0, stream>>>(wgsum, binstart);
        scanC_kernel<<<SCAN_WGS, 256, 0, stream>>>(hist, wgsum, binstart, cursor);
        binpass_kernel<1><<<NPTS/256, 256, 0, stream>>>(Wf, bf, rv, inds, hbuf,
                                                        cursor, coords_s);
        region_kernel<<<REG_PER_B*BATCH, 256, 0, stream>>>(coords_s, binstart, out);
    } else {
        hipMemsetAsync(d_out, 0, (size_t)out_size * sizeof(float), stream);
        scatter_fallback<<<NPTS/256, 256, 0, stream>>>(Wf, bf, rv, inds, hbuf, out);
    }
}

// Round 15
// 200.781 us; speedup vs baseline: 1.8772x; 1.8772x over previous
//
#include <hip/hip_runtime.h>
#include <math.h>

#define VOL   128
#define V2    (VOL*VOL)
#define V3    (VOL*VOL*VOL)
#define NPTS  262144
#define LATD  16
#define BATCH 8
#define FACTORF 64.0f
#define NBINS (VOL*VOL)
#define RZ 8
#define RY 8
#define NREG_TOTAL 2048       // 16x16 regions x 8 batches
#define REGION_WGS 1280       // 5 wg/CU x 256 CU, persistent work-queue
#define FAR_CAP 8192

// ws layout (bytes)
#define WS_HBUF    0u
#define WS_HIST    256u                          // 16384*4 = 65536
#define WS_START   65792u                        // (16385)*4 -> pad
#define WS_RANK    131344u                       // NPTS*4
#define WS_KEYS    1179920u                      // NPTS*2 (ushort)
#define WS_CTRL    1704208u                      // farcnt@+0, workq@+4
#define WS_FARLIST 1704240u                      // FAR_CAP*4
#define WS_COORDS  1737008u                      // NPTS*BATCH*16
#define WS_FULL    35291440u

// Round-to-nearest-even float -> bf16 -> float (ml_dtypes / XLA bf16 RNE)
__device__ __forceinline__ float bf16r(float x) {
    unsigned u = __float_as_uint(x);
    u = (u + 0x7fffu + ((u >> 16) & 1u)) & 0xffff0000u;
    return __uint_as_float(u);
}

// SIREN MLP, per-op bf16 (verified round 11).
__global__ void mlp_kernel(const float* __restrict__ x,
                           const float* __restrict__ W0,
                           const float* __restrict__ b0,
                           const float* __restrict__ Wh,
                           const float* __restrict__ bh,
                           float* __restrict__ hout) {
    int b = threadIdx.x;
    if (b >= BATCH) return;
    float xb[LATD];
    #pragma unroll
    for (int i = 0; i < LATD; ++i) xb[i] = bf16r(x[b*LATD + i]);
    float h[8];
    #pragma unroll
    for (int j = 0; j < 8; ++j) {
        float acc = 0.f;
        #pragma unroll
        for (int i = 0; i < LATD; ++i) acc += xb[i] * bf16r(W0[i*8 + j]);
        float t = bf16r(acc);
        t = bf16r(t + bf16r(b0[j]));
        t = bf16r(30.0f * t);
        h[j] = bf16r(sinf(t));
    }
    for (int l = 0; l < 4; ++l) {
        float nh[8];
        #pragma unroll
        for (int j = 0; j < 8; ++j) {
            float acc = 0.f;
            #pragma unroll
            for (int r = 0; r < 8; ++r) acc += h[r] * bf16r(Wh[(l*8 + r)*8 + j]);
            float t = bf16r(acc);
            t = bf16r(t + bf16r(bh[l*8 + j]));
            float s = bf16r(sinf(t));
            nh[j] = bf16r(h[j] + s);
        }
        #pragma unroll
        for (int j = 0; j < 8; ++j) h[j] = nh[j];
    }
    #pragma unroll
    for (int j = 0; j < 8; ++j) hout[b*8 + j] = h[j];
}

// Histogram of source bins + within-bin rank (fused).
__global__ __launch_bounds__(256) void hist_rank_kernel(const int* __restrict__ inds,
                                                        unsigned* __restrict__ hist,
                                                        unsigned* __restrict__ rank) {
    int n = blockIdx.x * 256 + threadIdx.x;
    if (n >= NPTS) return;
    rank[n] = atomicAdd(&hist[inds[n*3]*VOL + inds[n*3+1]], 1u);
}

// Single-block exclusive scan over 16384 bins; also zeroes control words.
__global__ __launch_bounds__(256) void scan_kernel(const unsigned* __restrict__ hist,
                                                   unsigned* __restrict__ binstart,
                                                   unsigned* __restrict__ ctrl) {
    __shared__ unsigned part[256];
    int t = threadIdx.x;
    const int CH = NBINS / 256;
    unsigned s = 0;
    for (int k = 0; k < CH; ++k) s += hist[t*CH + k];
    part[t] = s; __syncthreads();
    for (int off = 1; off < 256; off <<= 1) {
        unsigned v = (t >= off) ? part[t - off] : 0u;
        __syncthreads();
        part[t] += v;
        __syncthreads();
    }
    unsigned run = (t == 0) ? 0u : part[t - 1];
    for (int k = 0; k < CH; ++k) {
        int idx = t*CH + k;
        binstart[idx] = run;
        run += hist[idx];
    }
    if (t == 0) { binstart[NBINS] = NPTS; ctrl[0] = 0u; ctrl[1] = 0u; }
}

// Per point: coords for all 8 batches into bin-sorted planes; far detection.
__global__ __launch_bounds__(256) void coords_kernel(
    const float* __restrict__ Wf, const float* __restrict__ bfv_g,
    const float* __restrict__ rv, const int* __restrict__ inds,
    const float* __restrict__ hbuf, const unsigned* __restrict__ binstart,
    const unsigned* __restrict__ rank, unsigned short* __restrict__ keys,
    unsigned* __restrict__ ctrl, unsigned* __restrict__ farlist,
    float4* __restrict__ coords_s)
{
    __shared__ float hs[64];
    if (threadIdx.x < 64) hs[threadIdx.x] = hbuf[threadIdx.x];
    __syncthreads();
    int n = blockIdx.x * 256 + threadIdx.x;
    if (n >= NPTS) return;
    int iz = inds[n*3], iy = inds[n*3+1], ix = inds[n*3+2];
    float cnx = ((float)ix - FACTORF) / FACTORF;
    float cny = ((float)iy - FACTORF) / FACTORF;
    float cnz = ((float)iz - FACTORF) / FACTORF;
    float val0 = rv[n];
    float4 bfv = ((const float4*)bfv_g)[n];
    float4 wf[8];
    #pragma unroll
    for (int r = 0; r < 8; ++r)
        wf[r] = ((const float4*)(Wf + (size_t)r * 4 * NPTS))[n];
    unsigned pos = binstart[iz*VOL + iy] + rank[n];
    keys[pos] = (unsigned short)((iz << 7) | iy);
    #pragma unroll
    for (int b = 0; b < BATCH; ++b) {
        float o0 = bfv.x, o1 = bfv.y, o2 = bfv.z, o3 = bfv.w;
        #pragma unroll
        for (int r = 0; r < 8; ++r) {
            float hv = hs[b*8 + r];
            o0 = fmaf(hv, wf[r].x, o0);
            o1 = fmaf(hv, wf[r].y, o1);
            o2 = fmaf(hv, wf[r].z, o2);
            o3 = fmaf(hv, wf[r].w, o3);
        }
        float4 c;
        c.x = FACTORF * (cnx + o0) + FACTORF;
        c.y = FACTORF * (cny + o1) + FACTORF;
        c.z = FACTORF * (cnz + o2) + FACTORF;
        c.w = val0 + o3;
        coords_s[(size_t)b * NPTS + pos] = c;
        int bz = (int)floorf(c.z), by = (int)floorf(c.y);
        bool nearzy = ((unsigned)(bz - iz + 2) <= 4u) &&
                      ((unsigned)(by - iy + 2) <= 4u);
        if (!nearzy) {
            unsigned fp = atomicAdd(&ctrl[0], 1u);
            if (fp < FAR_CAP) farlist[fp] = (pos << 3) | (unsigned)b;
        }
    }
}

// Persistent work-queue region kernel: one pop = (batch, 8z x 8y x 128x region).
__global__ __launch_bounds__(256) void region_kernel(
    const float4* __restrict__ coords_s, const unsigned short* __restrict__ keys,
    const unsigned* __restrict__ binstart, unsigned* __restrict__ ctrl,
    float* __restrict__ out)
{
    __shared__ float tile[RZ*RY*VOL];   // 32 KB
    __shared__ int reg_s;
    int tid = threadIdx.x;

    const int ox[8] = {0,1,0,0,0,1,1,1};
    const int oy[8] = {0,0,1,0,1,0,1,1};
    const int oz[8] = {0,0,0,1,1,1,0,1};

    for (;;) {
        __syncthreads();
        if (tid == 0) reg_s = (int)atomicAdd(&ctrl[1], 1u);
        __syncthreads();
        int reg = reg_s;
        if (reg >= NREG_TOTAL) return;
        int b   = reg >> 8;
        int rid = reg & 255;
        int z0 = (rid >> 4) * RZ, y0 = (rid & 15) * RY;

        for (int i = tid; i < RZ*RY*VOL; i += 256) tile[i] = 0.f;
        __syncthreads();

        int ylo = y0 - 3, yhi = y0 + RY + 2;
        int sA0, sA1, sB0, sB1;
        if (ylo < 0)        { sA0 = ylo + VOL; sA1 = VOL; sB0 = 0; sB1 = yhi; }
        else if (yhi > VOL) { sA0 = ylo; sA1 = VOL; sB0 = 0; sB1 = yhi - VOL; }
        else                { sA0 = ylo; sA1 = yhi; sB0 = 0; sB1 = 0; }

        const float4* cb = coords_s + (size_t)b * NPTS;

        for (int zr = z0 - 3; zr < z0 + RZ + 2; ++zr) {
            int zz = (zr + VOL) & (VOL-1);
            int base = zz * VOL;
            for (int sg = 0; sg < 2; ++sg) {
                int a  = sg ? sB0 : sA0;
                int e2 = sg ? sB1 : sA1;
                if (a >= e2) continue;
                unsigned s = binstart[base + a];
                unsigned e = binstart[base + e2];
                for (unsigned i = s + tid; i < e; i += 256) {
                    unsigned kv = keys[i];
                    int piz = (int)(kv >> 7), piy = (int)(kv & 127);
                    float4 c = cb[i];
                    float fxf = floorf(c.x), fyf = floorf(c.y), fzf = floorf(c.z);
                    int bx = (int)fxf, by = (int)fyf, bz = (int)fzf;
                    bool nearzy = ((unsigned)(bz - piz + 2) <= 4u) &&
                                  ((unsigned)(by - piy + 2) <= 4u);
                    if (!nearzy) continue;
                    float fx = c.x - fxf, fy = c.y - fyf, fz = c.z - fzf;
                    float gx = 1.f - fx, gy = 1.f - fy, gz = 1.f - fz;
                    float val = c.w;
                    float w[8] = {gx*gy*gz, fx*gy*gz, gx*fy*gz, gx*gy*fz,
                                  gx*fy*fz, fx*gy*fz, fx*fy*gz, fx*fy*fz};
                    #pragma unroll
                    for (int o = 0; o < 8; ++o) {
                        int Z = (bz + oz[o]) & 127, dz = Z - z0;
                        if ((unsigned)dz >= RZ) continue;
                        int Y = (by + oy[o]) & 127, dy = Y - y0;
                        if ((unsigned)dy >= RY) continue;
                        int X = (bx + ox[o]) & 127;
                        atomicAdd(&tile[(dz << 10) + (dy << 7) + X], val * w[o]);
                    }
                }
            }
        }
        __syncthreads();
        size_t ob = (size_t)b * V3;
        for (int i = tid; i < RZ*RY*VOL; i += 256) {
            int lz = i >> 10, ly = (i >> 7) & (RY-1), lx = i & 127;
            out[ob + (size_t)(z0+lz)*V2 + (y0+ly)*VOL + lx] = tile[i];
        }
    }
}

// Cleanup for far-displaced entries (expected ~0-10).
__global__ __launch_bounds__(256) void far_kernel(
    const float4* __restrict__ coords_s, const unsigned* __restrict__ ctrl,
    const unsigned* __restrict__ farlist, float* __restrict__ out)
{
    unsigned cnt = ctrl[0];
    if (cnt > FAR_CAP) cnt = FAR_CAP;
    const int ox[8] = {0,1,0,0,0,1,1,1};
    const int oy[8] = {0,0,1,0,1,0,1,1};
    const int oz[8] = {0,0,0,1,1,1,0,1};
    for (unsigned idx = blockIdx.x * 256 + threadIdx.x; idx < cnt;
         idx += gridDim.x * 256) {
        unsigned e = farlist[idx];
        unsigned pos = e >> 3;
        int b = (int)(e & 7u);
        float4 c = coords_s[(size_t)b * NPTS + pos];
        float fxf = floorf(c.x), fyf = floorf(c.y), fzf = floorf(c.z);
        int bx = (int)fxf, by = (int)fyf, bz = (int)fzf;
        float fx = c.x - fxf, fy = c.y - fyf, fz = c.z - fzf;
        float gx = 1.f - fx, gy = 1.f - fy, gz = 1.f - fz;
        float val = c.w;
        float w[8] = {gx*gy*gz, fx*gy*gz, gx*fy*gz, gx*gy*fz,
                      gx*fy*fz, fx*gy*fz, fx*fy*gz, fx*fy*fz};
        float* ob = out + (size_t)b * V3;
        #pragma unroll
        for (int o = 0; o < 8; ++o) {
            int Z = (bz + oz[o]) & 127;
            int Y = (by + oy[o]) & 127;
            int X = (bx + ox[o]) & 127;
            atomicAdd(ob + (size_t)Z*V2 + Y*VOL + X, val * w[o]);
        }
    }
}

// Fallback (round-11 verified path) if workspace too small.
__global__ __launch_bounds__(256) void scatter_fallback(
    const float* __restrict__ Wf, const float* __restrict__ bfv_g,
    const float* __restrict__ rv, const int* __restrict__ inds,
    const float* __restrict__ hbuf, float* __restrict__ out)
{
    __shared__ float hs[BATCH*8];
    if (threadIdx.x < BATCH*8) hs[threadIdx.x] = hbuf[threadIdx.x];
    __syncthreads();
    int n = blockIdx.x * blockDim.x + threadIdx.x;
    if (n >= NPTS) return;
    int iz = inds[n*3 + 0], iy = inds[n*3 + 1], ix = inds[n*3 + 2];
    float cnx = ((float)ix - FACTORF) / FACTORF;
    float cny = ((float)iy - FACTORF) / FACTORF;
    float cnz = ((float)iz - FACTORF) / FACTORF;
    float val0 = rv[n];
    float4 bfv = ((const float4*)bfv_g)[n];
    float4 wf[8];
    #pragma unroll
    for (int r = 0; r < 8; ++r)
        wf[r] = ((const float4*)(Wf + (size_t)r * 4 * NPTS))[n];
    static const int offs[8][3] = {{0,0,0},{1,0,0},{0,1,0},{0,0,1},
                                   {0,1,1},{1,0,1},{1,1,0},{1,1,1}};
    #pragma unroll
    for (int b = 0; b < BATCH; ++b) {
        float o0 = bfv.x, o1 = bfv.y, o2 = bfv.z, o3 = bfv.w;
        #pragma unroll
        for (int r = 0; r < 8; ++r) {
            float hv = hs[b*8 + r];
            o0 = fmaf(hv, wf[r].x, o0);
            o1 = fmaf(hv, wf[r].y, o1);
            o2 = fmaf(hv, wf[r].z, o2);
            o3 = fmaf(hv, wf[r].w, o3);
        }
        float cx = FACTORF * (cnx + o0) + FACTORF;
        float cy = FACTORF * (cny + o1) + FACTORF;
        float cz = FACTORF * (cnz + o2) + FACTORF;
        float val = val0 + o3;
        float fxf = floorf(cx), fyf = floorf(cy), fzf = floorf(cz);
        int bx = (int)fxf, by = (int)fyf, bz = (int)fzf;
        float fx = cx - fxf, fy = cy - fyf, fz = cz - fzf;
        float gx = 1.f - fx, gy = 1.f - fy, gz = 1.f - fz;
        float w[8] = {gx*gy*gz, fx*gy*gz, gx*fy*gz, gx*gy*fz,
                      gx*fy*fz, fx*gy*fz, fx*fy*gz, fx*fy*fz};
        float* ob = out + (size_t)b * V3;
        #pragma unroll
        for (int o = 0; o < 8; ++o) {
            int X = (bx + offs[o][0]) & (VOL-1);
            int Y = (by + offs[o][1]) & (VOL-1);
            int Z = (bz + offs[o][2]) & (VOL-1);
            atomicAdd(ob + (size_t)Z*V2 + Y*VOL + X, val * w[o]);
        }
    }
}

extern "C" void kernel_launch(void* const* d_in, const int* in_sizes, int n_in,
                              void* d_out, int out_size, void* d_ws, size_t ws_size,
                              hipStream_t stream) {
    const float* x    = (const float*)d_in[0];
    const float* W0   = (const float*)d_in[1];
    const float* b0   = (const float*)d_in[2];
    const float* Wh   = (const float*)d_in[3];
    const float* bh   = (const float*)d_in[4];
    const float* Wf   = (const float*)d_in[5];
    const float* bf   = (const float*)d_in[6];
    const float* rv   = (const float*)d_in[7];
    const int*   inds = (const int*)d_in[8];
    float* out = (float*)d_out;
    char*  ws  = (char*)d_ws;

    float*          hbuf     = (float*)(ws + WS_HBUF);
    unsigned*       hist     = (unsigned*)(ws + WS_HIST);
    unsigned*       binstart = (unsigned*)(ws + WS_START);
    unsigned*       rank     = (unsigned*)(ws + WS_RANK);
    unsigned short* keys     = (unsigned short*)(ws + WS_KEYS);
    unsigned*       ctrl     = (unsigned*)(ws + WS_CTRL);
    unsigned*       farlist  = (unsigned*)(ws + WS_FARLIST);
    float4*         coords_s = (float4*)(ws + WS_COORDS);

    mlp_kernel<<<1, 64, 0, stream>>>(x, W0, b0, Wh, bh, hbuf);

    if (ws_size >= (size_t)WS_FULL) {
        hipMemsetAsync(hist, 0, NBINS*4, stream);
        hist_rank_kernel<<<NPTS/256, 256, 0, stream>>>(inds, hist, rank);
        scan_kernel<<<1, 256, 0, stream>>>(hist, binstart, ctrl);
        coords_kernel<<<NPTS/256, 256, 0, stream>>>(Wf, bf, rv, inds, hbuf,
                                                    binstart, rank, keys,
                                                    ctrl, farlist, coords_s);
        region_kernel<<<REGION_WGS, 256, 0, stream>>>(coords_s, keys, binstart,
                                                      ctrl, out);
        far_kernel<<<8, 256, 0, stream>>>(coords_s, ctrl, farlist, out);
    } else {
        hipMemsetAsync(d_out, 0, (size_t)out_size * sizeof(float), stream);
        scatter_fallback<<<NPTS/256, 256, 0, stream>>>(Wf, bf, rv, inds, hbuf, out);
    }
}

// Round 16
// 179.938 us; speedup vs baseline: 2.0946x; 1.1158x over previous
//
#include <hip/hip_runtime.h>
#include <math.h>

#define VOL   128
#define V2    (VOL*VOL)
#define V3    (VOL*VOL*VOL)
#define NPTS  262144
#define LATD  16
#define BATCH 8
#define FACTORF 64.0f
#define NBINS (VOL*VOL)
#define RZ 8
#define RY 4
#define REG_PER_B ((VOL/RZ)*(VOL/RY))   // 512
#define FAR_CAP 8192

// ws layout (bytes)
#define WS_HBUF    0u
#define WS_HIST    256u
#define WS_START   65792u
#define WS_RANK    131344u
#define WS_KEYS    1179920u
#define WS_CTRL    1704208u
#define WS_FARLIST 1704240u
#define WS_COORDS  1737008u
#define WS_FULL    35291440u

// Round-to-nearest-even float -> bf16 -> float (ml_dtypes / XLA bf16 RNE)
__device__ __forceinline__ float bf16r(float x) {
    unsigned u = __float_as_uint(x);
    u = (u + 0x7fffu + ((u >> 16) & 1u)) & 0xffff0000u;
    return __uint_as_float(u);
}

// SIREN MLP, per-op bf16 (verified round 11).
__global__ void mlp_kernel(const float* __restrict__ x,
                           const float* __restrict__ W0,
                           const float* __restrict__ b0,
                           const float* __restrict__ Wh,
                           const float* __restrict__ bh,
                           float* __restrict__ hout) {
    int b = threadIdx.x;
    if (b >= BATCH) return;
    float xb[LATD];
    #pragma unroll
    for (int i = 0; i < LATD; ++i) xb[i] = bf16r(x[b*LATD + i]);
    float h[8];
    #pragma unroll
    for (int j = 0; j < 8; ++j) {
        float acc = 0.f;
        #pragma unroll
        for (int i = 0; i < LATD; ++i) acc += xb[i] * bf16r(W0[i*8 + j]);
        float t = bf16r(acc);
        t = bf16r(t + bf16r(b0[j]));
        t = bf16r(30.0f * t);
        h[j] = bf16r(sinf(t));
    }
    for (int l = 0; l < 4; ++l) {
        float nh[8];
        #pragma unroll
        for (int j = 0; j < 8; ++j) {
            float acc = 0.f;
            #pragma unroll
            for (int r = 0; r < 8; ++r) acc += h[r] * bf16r(Wh[(l*8 + r)*8 + j]);
            float t = bf16r(acc);
            t = bf16r(t + bf16r(bh[l*8 + j]));
            float s = bf16r(sinf(t));
            nh[j] = bf16r(h[j] + s);
        }
        #pragma unroll
        for (int j = 0; j < 8; ++j) h[j] = nh[j];
    }
    #pragma unroll
    for (int j = 0; j < 8; ++j) hout[b*8 + j] = h[j];
}

// Histogram of source bins + within-bin rank (fused).
__global__ __launch_bounds__(256) void hist_rank_kernel(const int* __restrict__ inds,
                                                        unsigned* __restrict__ hist,
                                                        unsigned* __restrict__ rank) {
    int n = blockIdx.x * 256 + threadIdx.x;
    if (n >= NPTS) return;
    rank[n] = atomicAdd(&hist[inds[n*3]*VOL + inds[n*3+1]], 1u);
}

// Single-block exclusive scan over 16384 bins; also zeroes control words.
__global__ __launch_bounds__(256) void scan_kernel(const unsigned* __restrict__ hist,
                                                   unsigned* __restrict__ binstart,
                                                   unsigned* __restrict__ ctrl) {
    __shared__ unsigned part[256];
    int t = threadIdx.x;
    const int CH = NBINS / 256;
    unsigned s = 0;
    for (int k = 0; k < CH; ++k) s += hist[t*CH + k];
    part[t] = s; __syncthreads();
    for (int off = 1; off < 256; off <<= 1) {
        unsigned v = (t >= off) ? part[t - off] : 0u;
        __syncthreads();
        part[t] += v;
        __syncthreads();
    }
    unsigned run = (t == 0) ? 0u : part[t - 1];
    for (int k = 0; k < CH; ++k) {
        int idx = t*CH + k;
        binstart[idx] = run;
        run += hist[idx];
    }
    if (t == 0) { binstart[NBINS] = NPTS; ctrl[0] = 0u; ctrl[1] = 0u; }
}

// Per point: coords for all 8 batches into bin-sorted planes; far detection.
__global__ __launch_bounds__(256) void coords_kernel(
    const float* __restrict__ Wf, const float* __restrict__ bfv_g,
    const float* __restrict__ rv, const int* __restrict__ inds,
    const float* __restrict__ hbuf, const unsigned* __restrict__ binstart,
    const unsigned* __restrict__ rank, unsigned short* __restrict__ keys,
    unsigned* __restrict__ ctrl, unsigned* __restrict__ farlist,
    float4* __restrict__ coords_s)
{
    __shared__ float hs[64];
    if (threadIdx.x < 64) hs[threadIdx.x] = hbuf[threadIdx.x];
    __syncthreads();
    int n = blockIdx.x * 256 + threadIdx.x;
    if (n >= NPTS) return;
    int iz = inds[n*3], iy = inds[n*3+1], ix = inds[n*3+2];
    float cnx = ((float)ix - FACTORF) / FACTORF;
    float cny = ((float)iy - FACTORF) / FACTORF;
    float cnz = ((float)iz - FACTORF) / FACTORF;
    float val0 = rv[n];
    float4 bfv = ((const float4*)bfv_g)[n];
    float4 wf[8];
    #pragma unroll
    for (int r = 0; r < 8; ++r)
        wf[r] = ((const float4*)(Wf + (size_t)r * 4 * NPTS))[n];
    unsigned pos = binstart[iz*VOL + iy] + rank[n];
    keys[pos] = (unsigned short)((iz << 7) | iy);
    #pragma unroll
    for (int b = 0; b < BATCH; ++b) {
        float o0 = bfv.x, o1 = bfv.y, o2 = bfv.z, o3 = bfv.w;
        #pragma unroll
        for (int r = 0; r < 8; ++r) {
            float hv = hs[b*8 + r];
            o0 = fmaf(hv, wf[r].x, o0);
            o1 = fmaf(hv, wf[r].y, o1);
            o2 = fmaf(hv, wf[r].z, o2);
            o3 = fmaf(hv, wf[r].w, o3);
        }
        float4 c;
        c.x = FACTORF * (cnx + o0) + FACTORF;
        c.y = FACTORF * (cny + o1) + FACTORF;
        c.z = FACTORF * (cnz + o2) + FACTORF;
        c.w = val0 + o3;
        coords_s[(size_t)b * NPTS + pos] = c;
        int bz = (int)floorf(c.z), by = (int)floorf(c.y);
        bool nearzy = ((unsigned)(bz - iz + 2) <= 4u) &&
                      ((unsigned)(by - iy + 2) <= 4u);
        if (!nearzy) {
            unsigned fp = atomicAdd(&ctrl[0], 1u);
            if (fp < FAR_CAP) farlist[fp] = (pos << 3) | (unsigned)b;
        }
    }
}

// One wg = (batch, RZ x RY x 128 region). Flattened halo scan + 4-way ILP.
__global__ __launch_bounds__(256) void region_kernel(
    const float4* __restrict__ coords_s, const unsigned short* __restrict__ keys,
    const unsigned* __restrict__ binstart, float* __restrict__ out)
{
    __shared__ float tile[RZ*RY*VOL];   // 16 KB
    __shared__ unsigned rstart[26], rcnt[26], rcum[27];
    int tid = threadIdx.x;
    int b   = blockIdx.x >> 9;
    int rid = blockIdx.x & (REG_PER_B - 1);
    int z0 = (rid >> 5) * RZ, y0 = (rid & 31) * RY;

    for (int i = tid; i < RZ*RY*VOL; i += 256) tile[i] = 0.f;

    if (tid < 13) {
        int zr = z0 - 3 + tid;
        int zz = (zr + VOL) & (VOL-1);
        int base = zz * VOL;
        int ylo = y0 - 3, yhi = y0 + RY + 2;
        int a0, a1, b0, b1;
        if (ylo < 0)        { a0 = ylo + VOL; a1 = VOL; b0 = 0; b1 = yhi; }
        else if (yhi > VOL) { a0 = ylo; a1 = VOL; b0 = 0; b1 = yhi - VOL; }
        else                { a0 = ylo; a1 = yhi; b0 = 0; b1 = 0; }
        unsigned sA = binstart[base + a0];
        rstart[tid*2]   = sA;
        rcnt[tid*2]     = binstart[base + a1] - sA;
        unsigned sB = binstart[base + b0];
        rstart[tid*2+1] = sB;
        rcnt[tid*2+1]   = (b1 > b0) ? (binstart[base + b1] - sB) : 0u;
    }
    __syncthreads();
    if (tid == 0) {
        unsigned run = 0;
        #pragma unroll
        for (int r = 0; r < 26; ++r) { rcum[r] = run; run += rcnt[r]; }
        rcum[26] = run;
    }
    __syncthreads();

    const int ox[8] = {0,1,0,0,0,1,1,1};
    const int oy[8] = {0,0,1,0,1,0,1,1};
    const int oz[8] = {0,0,0,1,1,1,0,1};
    const float4* cb = coords_s + (size_t)b * NPTS;

    unsigned total = rcum[26];
    int r = 0;
    for (unsigned f = tid; f < total; f += 1024) {
        float4 c[4]; unsigned kk[4]; bool v[4];
        #pragma unroll
        for (int u = 0; u < 4; ++u) {
            unsigned fu = f + (unsigned)u * 256u;
            v[u] = fu < total;
            if (v[u]) {
                while (fu >= rcum[r+1]) ++r;
                unsigned j = rstart[r] + (fu - rcum[r]);
                c[u]  = cb[j];
                kk[u] = keys[j];
            }
        }
        #pragma unroll
        for (int u = 0; u < 4; ++u) {
            if (!v[u]) continue;
            int piz = (int)(kk[u] >> 7), piy = (int)(kk[u] & 127u);
            float4 cc = c[u];
            float fxf = floorf(cc.x), fyf = floorf(cc.y), fzf = floorf(cc.z);
            int bx = (int)fxf, by = (int)fyf, bz = (int)fzf;
            bool nearzy = ((unsigned)(bz - piz + 2) <= 4u) &&
                          ((unsigned)(by - piy + 2) <= 4u);
            if (!nearzy) continue;
            float fx = cc.x - fxf, fy = cc.y - fyf, fz = cc.z - fzf;
            float gx = 1.f - fx, gy = 1.f - fy, gz = 1.f - fz;
            float val = cc.w;
            float w[8] = {gx*gy*gz, fx*gy*gz, gx*fy*gz, gx*gy*fz,
                          gx*fy*fz, fx*gy*fz, fx*fy*gz, fx*fy*fz};
            #pragma unroll
            for (int o = 0; o < 8; ++o) {
                int Z = (bz + oz[o]) & 127, dz = Z - z0;
                if ((unsigned)dz >= RZ) continue;
                int Y = (by + oy[o]) & 127, dy = Y - y0;
                if ((unsigned)dy >= RY) continue;
                int X = (bx + ox[o]) & 127;
                atomicAdd(&tile[(dz << 9) + (dy << 7) + X], val * w[o]);
            }
        }
    }
    __syncthreads();
    size_t ob = (size_t)b * V3;
    for (int i = tid; i < RZ*RY*VOL; i += 256) {
        int lz = i >> 9, ly = (i >> 7) & (RY-1), lx = i & 127;
        out[ob + (size_t)(z0+lz)*V2 + (y0+ly)*VOL + lx] = tile[i];
    }
}

// Cleanup for far-displaced entries (expected ~0-10).
__global__ __launch_bounds__(256) void far_kernel(
    const float4* __restrict__ coords_s, const unsigned* __restrict__ ctrl,
    const unsigned* __restrict__ farlist, float* __restrict__ out)
{
    unsigned cnt = ctrl[0];
    if (cnt > FAR_CAP) cnt = FAR_CAP;
    const int ox[8] = {0,1,0,0,0,1,1,1};
    const int oy[8] = {0,0,1,0,1,0,1,1};
    const int oz[8] = {0,0,0,1,1,1,0,1};
    for (unsigned idx = blockIdx.x * 256 + threadIdx.x; idx < cnt;
         idx += gridDim.x * 256) {
        unsigned e = farlist[idx];
        unsigned pos = e >> 3;
        int b = (int)(e & 7u);
        float4 c = coords_s[(size_t)b * NPTS + pos];
        float fxf = floorf(c.x), fyf = floorf(c.y), fzf = floorf(c.z);
        int bx = (int)fxf, by = (int)fyf, bz = (int)fzf;
        float fx = c.x - fxf, fy = c.y - fyf, fz = c.z - fzf;
        float gx = 1.f - fx, gy = 1.f - fy, gz = 1.f - fz;
        float val = c.w;
        float w[8] = {gx*gy*gz, fx*gy*gz, gx*fy*gz, gx*gy*fz,
                      gx*fy*fz, fx*gy*fz, fx*fy*gz, fx*fy*fz};
        float* ob = out + (size_t)b * V3;
        #pragma unroll
        for (int o = 0; o < 8; ++o) {
            int Z = (bz + oz[o]) & 127;
            int Y = (by + oy[o]) & 127;
            int X = (bx + ox[o]) & 127;
            atomicAdd(ob + (size_t)Z*V2 + Y*VOL + X, val * w[o]);
        }
    }
}

// Fallback (round-11 verified path) if workspace too small.
__global__ __launch_bounds__(256) void scatter_fallback(
    const float* __restrict__ Wf, const float* __restrict__ bfv_g,
    const float* __restrict__ rv, const int* __restrict__ inds,
    const float* __restrict__ hbuf, float* __restrict__ out)
{
    __shared__ float hs[BATCH*8];
    if (threadIdx.x < BATCH*8) hs[threadIdx.x] = hbuf[threadIdx.x];
    __syncthreads();
    int n = blockIdx.x * blockDim.x + threadIdx.x;
    if (n >= NPTS) return;
    int iz = inds[n*3 + 0], iy = inds[n*3 + 1], ix = inds[n*3 + 2];
    float cnx = ((float)ix - FACTORF) / FACTORF;
    float cny = ((float)iy - FACTORF) / FACTORF;
    float cnz = ((float)iz - FACTORF) / FACTORF;
    float val0 = rv[n];
    float4 bfv = ((const float4*)bfv_g)[n];
    float4 wf[8];
    #pragma unroll
    for (int r = 0; r < 8; ++r)
        wf[r] = ((const float4*)(Wf + (size_t)r * 4 * NPTS))[n];
    static const int offs[8][3] = {{0,0,0},{1,0,0},{0,1,0},{0,0,1},
                                   {0,1,1},{1,0,1},{1,1,0},{1,1,1}};
    #pragma unroll
    for (int b = 0; b < BATCH; ++b) {
        float o0 = bfv.x, o1 = bfv.y, o2 = bfv.z, o3 = bfv.w;
        #pragma unroll
        for (int r = 0; r < 8; ++r) {
            float hv = hs[b*8 + r];
            o0 = fmaf(hv, wf[r].x, o0);
            o1 = fmaf(hv, wf[r].y, o1);
            o2 = fmaf(hv, wf[r].z, o2);
            o3 = fmaf(hv, wf[r].w, o3);
        }
        float cx = FACTORF * (cnx + o0) + FACTORF;
        float cy = FACTORF * (cny + o1) + FACTORF;
        float cz = FACTORF * (cnz + o2) + FACTORF;
        float val = val0 + o3;
        float fxf = floorf(cx), fyf = floorf(cy), fzf = floorf(cz);
        int bx = (int)fxf, by = (int)fyf, bz = (int)fzf;
        float fx = cx - fxf, fy = cy - fyf, fz = cz - fzf;
        float gx = 1.f - fx, gy = 1.f - fy, gz = 1.f - fz;
        float w[8] = {gx*gy*gz, fx*gy*gz, gx*fy*gz, gx*gy*fz,
                      gx*fy*fz, fx*gy*fz, fx*fy*gz, fx*fy*fz};
        float* ob = out + (size_t)b * V3;
        #pragma unroll
        for (int o = 0; o < 8; ++o) {
            int X = (bx + offs[o][0]) & (VOL-1);
            int Y = (by + offs[o][1]) & (VOL-1);
            int Z = (bz + offs[o][2]) & (VOL-1);
            atomicAdd(ob + (size_t)Z*V2 + Y*VOL + X, val * w[o]);
        }
    }
}

extern "C" void kernel_launch(void* const* d_in, const int* in_sizes, int n_in,
                              void* d_out, int out_size, void* d_ws, size_t ws_size,
                              hipStream_t stream) {
    const float* x    = (const float*)d_in[0];
    const float* W0   = (const float*)d_in[1];
    const float* b0   = (const float*)d_in[2];
    const float* Wh   = (const float*)d_in[3];
    const float* bh   = (const float*)d_in[4];
    const float* Wf   = (const float*)d_in[5];
    const float* bf   = (const float*)d_in[6];
    const float* rv   = (const float*)d_in[7];
    const int*   inds = (const int*)d_in[8];
    float* out = (float*)d_out;
    char*  ws  = (char*)d_ws;

    float*          hbuf     = (float*)(ws + WS_HBUF);
    unsigned*       hist     = (unsigned*)(ws + WS_HIST);
    unsigned*       binstart = (unsigned*)(ws + WS_START);
    unsigned*       rank     = (unsigned*)(ws + WS_RANK);
    unsigned short* keys     = (unsigned short*)(ws + WS_KEYS);
    unsigned*       ctrl     = (unsigned*)(ws + WS_CTRL);
    unsigned*       farlist  = (unsigned*)(ws + WS_FARLIST);
    float4*         coords_s = (float4*)(ws + WS_COORDS);

    mlp_kernel<<<1, 64, 0, stream>>>(x, W0, b0, Wh, bh, hbuf);

    if (ws_size >= (size_t)WS_FULL) {
        hipMemsetAsync(hist, 0, NBINS*4, stream);
        hist_rank_kernel<<<NPTS/256, 256, 0, stream>>>(inds, hist, rank);
        scan_kernel<<<1, 256, 0, stream>>>(hist, binstart, ctrl);
        coords_kernel<<<NPTS/256, 256, 0, stream>>>(Wf, bf, rv, inds, hbuf,
                                                    binstart, rank, keys,
                                                    ctrl, farlist, coords_s);
        region_kernel<<<REG_PER_B*BATCH, 256, 0, stream>>>(coords_s, keys,
                                                           binstart, out);
        far_kernel<<<8, 256, 0, stream>>>(coords_s, ctrl, farlist, out);
    } else {
        hipMemsetAsync(d_out, 0, (size_t)out_size * sizeof(float), stream);
        scatter_fallback<<<NPTS/256, 256, 0, stream>>>(Wf, bf, rv, inds, hbuf, out);
    }
}